// Round 6
// baseline (481.643 us; speedup 1.0000x reference)
//
#include <hip/hip_runtime.h>
#include <hip/hip_bf16.h>

#define EMB 256
#define PRETRAIN 768
#define NLEV 8
#define BLK 12800  // 64*200 (B*L)

typedef __attribute__((ext_vector_type(8))) short short8t;
typedef __attribute__((ext_vector_type(4))) float f32x4;

// RNE float -> bf16 bits
static __device__ __forceinline__ unsigned short f2b(float f) {
    unsigned u = __builtin_bit_cast(unsigned, f);
    u += 0x7fffu + ((u >> 16) & 1u);
    return (unsigned short)(u >> 16);
}

// Blocks [0, BLK): one block per (b,l).
//   Waves 0-2: pool content rows (768 f32, float4/lane) -> pooled (bf16).
//   Wave 3:    pool cid rows (256 f32, float4/lane)     -> out (f32, cid part).
// Blocks [BLK, BLK+96): transpose-cast proj_w [768][256] f32 -> WT [256][768] bf16.
__global__ __launch_bounds__(256) void pool_kernel(
    const int* __restrict__ croutes,      // [BLK][8]
    const float* __restrict__ cid_emb,    // [100000][256]
    const float* __restrict__ weight,     // [8]
    const float* __restrict__ content,    // [100002][768]
    const float* __restrict__ proj_w,     // [768][256]
    unsigned short* __restrict__ pooled,  // bf16 bits [BLK][768]
    unsigned short* __restrict__ WT,      // bf16 bits [256][768]
    float* __restrict__ out)              // [BLK][256], cid part
{
    const int t = threadIdx.x;

    if (blockIdx.x >= BLK) {
        // ---- proj_w transpose-cast path ----
        const int g  = (blockIdx.x - BLK) * 256 + t;  // 0..24575
        const int n  = g & 255;
        const int kb = (g >> 8) << 3;                 // 0..760 step 8
        short8t v;
#pragma unroll
        for (int j = 0; j < 8; ++j)
            v[j] = (short)f2b(proj_w[(size_t)(kb + j) * EMB + n]);
        *(short8t*)(WT + (size_t)n * PRETRAIN + kb) = v;
        return;
    }

    const int bl = blockIdx.x;

    int   idx[NLEV];
    float alpha[NLEV];
    float m = -INFINITY;
#pragma unroll
    for (int k = 0; k < NLEV; ++k) {
        idx[k] = croutes[bl * NLEV + k] + 2;          // 0..100001; 0 == pad (-2)
        if (idx[k] != 0) m = fmaxf(m, weight[k]);
    }
    float s = 0.f;
#pragma unroll
    for (int k = 0; k < NLEV; ++k) {
        float e = (idx[k] != 0) ? expf(weight[k] - m) : 0.f;
        alpha[k] = e;
        s += e;
    }
    const float inv = 1.f / s;
#pragma unroll
    for (int k = 0; k < NLEV; ++k) alpha[k] *= inv;

    if (t < 192) {
        // content pooling: 192 threads * float4 = 768 floats
        float ax = 0.f, ay = 0.f, az = 0.f, aw = 0.f;
#pragma unroll
        for (int k = 0; k < NLEV; ++k) {
            if (idx[k] != 0) {                        // block-uniform branch
                const float4* row = (const float4*)(content + (size_t)idx[k] * PRETRAIN);
                float4 v = row[t];
                float  a = alpha[k];
                ax = fmaf(a, v.x, ax); ay = fmaf(a, v.y, ay);
                az = fmaf(a, v.z, az); aw = fmaf(a, v.w, aw);
            }
        }
        ushort4 o;
        o.x = f2b(ax); o.y = f2b(ay); o.z = f2b(az); o.w = f2b(aw);
        *(ushort4*)(pooled + (size_t)bl * PRETRAIN + t * 4) = o;
    } else {
        // cid pooling: 64 threads * float4 = 256 floats; cat rows 0/1 are zeros
        const int tc = t - 192;
        float ax = 0.f, ay = 0.f, az = 0.f, aw = 0.f;
#pragma unroll
        for (int k = 0; k < NLEV; ++k) {
            if (idx[k] >= 2) {
                const float4* row = (const float4*)(cid_emb + (size_t)(idx[k] - 2) * EMB);
                float4 v = row[tc];
                float  a = alpha[k];
                ax = fmaf(a, v.x, ax); ay = fmaf(a, v.y, ay);
                az = fmaf(a, v.z, az); aw = fmaf(a, v.w, aw);
            }
        }
        float4 o = {ax, ay, az, aw};
        *(float4*)(out + (size_t)bl * EMB + tc * 4) = o;
    }
}

// C[12800,256] = A[12800,768]bf16 @ W[768,256]bf16 + (cid part already in out) + proj_b
// BM=64, BN=128, BK=64; 4 waves in 2x2; each wave 32x64 via 2x4 frags of 16x16x32 MFMA.
__global__ __launch_bounds__(256) void gemm_kernel(
    const unsigned short* __restrict__ A,   // [12800][768] bf16 bits
    const unsigned short* __restrict__ WT,  // [256][768] bf16 bits (n-major)
    const float* __restrict__ proj_b,       // [256]
    float* __restrict__ out)                // [12800][256] (contains cid part)
{
    __shared__ char smem[8192 + 16384];
    char* sA = smem;          // [64 rows][64 k] bf16, XOR-swizzled
    char* sB = smem + 8192;   // [128 n][64 k] bf16, XOR-swizzled

    const int t    = threadIdx.x;
    const int lane = t & 63;
    const int wave = t >> 6;
    const int wr   = wave >> 1, wc = wave & 1;
    const int bm0  = blockIdx.x * 64;
    const int bn0  = blockIdx.y * 128;

    f32x4 acc[2][4] = {};

    for (int k0 = 0; k0 < PRETRAIN; k0 += 64) {
        // stage A: 512 x 16B chunks, 8 chunks per 128B row
#pragma unroll
        for (int i = 0; i < 2; ++i) {
            int c = t + i * 256;
            int row = c >> 3, cc = c & 7;
            short8t v = *(const short8t*)(A + (size_t)(bm0 + row) * PRETRAIN + k0 + cc * 8);
            *(short8t*)(sA + row * 128 + ((cc * 16) ^ ((row & 7) << 4))) = v;
        }
        // stage B: 1024 x 16B chunks
#pragma unroll
        for (int i = 0; i < 4; ++i) {
            int c = t + i * 256;
            int row = c >> 3, cc = c & 7;
            short8t v = *(const short8t*)(WT + (size_t)(bn0 + row) * PRETRAIN + k0 + cc * 8);
            *(short8t*)(sB + row * 128 + ((cc * 16) ^ ((row & 7) << 4))) = v;
        }
        __syncthreads();
#pragma unroll
        for (int ks = 0; ks < 2; ++ks) {
            const int kb = ks * 64 + (lane >> 4) * 16;   // byte offset of this lane's k-group
            short8t a[2], b[4];
#pragma unroll
            for (int mf = 0; mf < 2; ++mf) {
                int row = wr * 32 + mf * 16 + (lane & 15);
                a[mf] = *(const short8t*)(sA + row * 128 + (kb ^ ((row & 7) << 4)));
            }
#pragma unroll
            for (int nf = 0; nf < 4; ++nf) {
                int n = wc * 64 + nf * 16 + (lane & 15);
                b[nf] = *(const short8t*)(sB + n * 128 + (kb ^ ((n & 7) << 4)));
            }
#pragma unroll
            for (int mf = 0; mf < 2; ++mf)
#pragma unroll
                for (int nf = 0; nf < 4; ++nf)
                    acc[mf][nf] = __builtin_amdgcn_mfma_f32_16x16x32_bf16(
                        a[mf], b[nf], acc[mf][nf], 0, 0, 0);
        }
        __syncthreads();
    }

    // epilogue: out += acc + proj_b  (C/D layout: col=lane&15, row=(lane>>4)*4+i)
#pragma unroll
    for (int mf = 0; mf < 2; ++mf)
#pragma unroll
        for (int nf = 0; nf < 4; ++nf)
#pragma unroll
            for (int i = 0; i < 4; ++i) {
                int mrow = bm0 + wr * 32 + mf * 16 + (lane >> 4) * 4 + i;
                int ncol = bn0 + wc * 64 + nf * 16 + (lane & 15);
                size_t o = (size_t)mrow * EMB + ncol;
                out[o] = out[o] + acc[mf][nf][i] + proj_b[ncol];
            }
}

extern "C" void kernel_launch(void* const* d_in, const int* in_sizes, int n_in,
                              void* d_out, int out_size, void* d_ws, size_t ws_size,
                              hipStream_t stream) {
    const int*   croutes = (const int*)d_in[0];
    // d_in[1] = tailcs (unused by reference)
    const float* cid_emb = (const float*)d_in[2];
    const float* weight  = (const float*)d_in[3];
    const float* content = (const float*)d_in[4];
    const float* proj_w  = (const float*)d_in[5];
    const float* proj_b  = (const float*)d_in[6];
    float*       out     = (float*)d_out;

    char* ws = (char*)d_ws;
    unsigned short* pooled = (unsigned short*)ws;                      // 12800*768*2 = 19,660,800 B
    unsigned short* WT     = (unsigned short*)(ws + 19660800);         // 256*768*2  =    393,216 B

    pool_kernel<<<BLK + 96, 256, 0, stream>>>(croutes, cid_emb, weight, content,
                                              proj_w, pooled, WT, out);
    gemm_kernel<<<dim3(200, 2), 256, 0, stream>>>(pooled, WT, proj_b, out);
}

// Round 7
// 476.632 us; speedup vs baseline: 1.0105x; 1.0105x over previous
//
#include <hip/hip_runtime.h>
#include <hip/hip_bf16.h>

#define EMB 256
#define PRETRAIN 768
#define NLEV 8
#define BLK 12800  // 64*200 (B*L)

typedef __attribute__((ext_vector_type(8))) short short8t;
typedef __attribute__((ext_vector_type(4))) float f32x4;

// RNE float -> bf16 bits
static __device__ __forceinline__ unsigned short f2b(float f) {
    unsigned u = __builtin_bit_cast(unsigned, f);
    u += 0x7fffu + ((u >> 16) & 1u);
    return (unsigned short)(u >> 16);
}

// Blocks [0, BLK): one block per (b,l).
//   Waves 0-2: pool content rows (768 f32, float4/lane) -> pooled (bf16).
//   Wave 3:    pool cid rows (256 f32, float4/lane)     -> out (f32, cid part).
// Blocks [BLK, BLK+96): transpose-cast proj_w [768][256] f32 -> WT [256][768] bf16.
// Gathers are BRANCHLESS: pad levels have alpha==0 so loading the (valid) row
// and multiplying by 0 is exact; this lets all 8 row loads issue back-to-back
// instead of serializing behind exec-mask regions.
__global__ __launch_bounds__(256) void pool_kernel(
    const int* __restrict__ croutes,      // [BLK][8]
    const float* __restrict__ cid_emb,    // [100000][256]
    const float* __restrict__ weight,     // [8]
    const float* __restrict__ content,    // [100002][768]
    const float* __restrict__ proj_w,     // [768][256]
    unsigned short* __restrict__ pooled,  // bf16 bits [BLK][768]
    unsigned short* __restrict__ WT,      // bf16 bits [256][768]
    float* __restrict__ out)              // [BLK][256], cid part
{
    const int t = threadIdx.x;

    if (blockIdx.x >= BLK) {
        // ---- proj_w transpose-cast path ----
        const int g  = (blockIdx.x - BLK) * 256 + t;  // 0..24575
        const int n  = g & 255;
        const int kb = (g >> 8) << 3;                 // 0..760 step 8
        short8t v;
#pragma unroll
        for (int j = 0; j < 8; ++j)
            v[j] = (short)f2b(proj_w[(size_t)(kb + j) * EMB + n]);
        *(short8t*)(WT + (size_t)n * PRETRAIN + kb) = v;
        return;
    }

    const int bl = blockIdx.x;

    int   idx[NLEV];
    float alpha[NLEV];
    float m = -INFINITY;
#pragma unroll
    for (int k = 0; k < NLEV; ++k) {
        idx[k] = croutes[bl * NLEV + k] + 2;          // 0..100001; 0 == pad (-2)
        if (idx[k] != 0) m = fmaxf(m, weight[k]);
    }
    float s = 0.f;
#pragma unroll
    for (int k = 0; k < NLEV; ++k) {
        float e = (idx[k] != 0) ? expf(weight[k] - m) : 0.f;
        alpha[k] = e;
        s += e;
    }
    const float inv = 1.f / s;
#pragma unroll
    for (int k = 0; k < NLEV; ++k) alpha[k] *= inv;

    if (t < 192) {
        // content pooling: 192 threads * float4 = 768 floats; unconditional loads
        float4 v[NLEV];
#pragma unroll
        for (int k = 0; k < NLEV; ++k)
            v[k] = ((const float4*)(content + (size_t)idx[k] * PRETRAIN))[t];
        float ax = 0.f, ay = 0.f, az = 0.f, aw = 0.f;
#pragma unroll
        for (int k = 0; k < NLEV; ++k) {
            float a = alpha[k];
            ax = fmaf(a, v[k].x, ax); ay = fmaf(a, v[k].y, ay);
            az = fmaf(a, v[k].z, az); aw = fmaf(a, v[k].w, aw);
        }
        ushort4 o;
        o.x = f2b(ax); o.y = f2b(ay); o.z = f2b(az); o.w = f2b(aw);
        *(ushort4*)(pooled + (size_t)bl * PRETRAIN + t * 4) = o;
    } else {
        // cid pooling: 64 threads * float4; clamped index + zeroed alpha for rows 0/1
        const int tc = t - 192;
        float4 v[NLEV];
        float  a2[NLEV];
#pragma unroll
        for (int k = 0; k < NLEV; ++k) {
            int r   = idx[k] - 2;
            a2[k]   = (r >= 0) ? alpha[k] : 0.f;
            r       = (r < 0) ? 0 : r;
            v[k] = ((const float4*)(cid_emb + (size_t)r * EMB))[tc];
        }
        float ax = 0.f, ay = 0.f, az = 0.f, aw = 0.f;
#pragma unroll
        for (int k = 0; k < NLEV; ++k) {
            float a = a2[k];
            ax = fmaf(a, v[k].x, ax); ay = fmaf(a, v[k].y, ay);
            az = fmaf(a, v[k].z, az); aw = fmaf(a, v[k].w, aw);
        }
        float4 o = {ax, ay, az, aw};
        *(float4*)(out + (size_t)bl * EMB + tc * 4) = o;
    }
}

// C[12800,256] = A[12800,768]bf16 @ W[768,256]bf16 + (cid part in out) + proj_b
// BM=64, BN=64, BK=64 -> 800 blocks (3.1/CU load balance vs 1.6 before).
// Double-buffered LDS, prefetch next tile into regs before MFMA phase
// (T3 minimum 2-phase), one barrier per K-tile instead of two.
// 4 waves 2x2; each wave 32x32 via 2x2 frags of 16x16x32 MFMA.
__global__ __launch_bounds__(256) void gemm_kernel(
    const unsigned short* __restrict__ A,   // [12800][768] bf16 bits
    const unsigned short* __restrict__ WT,  // [256][768] bf16 bits (n-major)
    const float* __restrict__ proj_b,       // [256]
    float* __restrict__ out)                // [12800][256] (contains cid part)
{
    __shared__ char smem[32768];            // 2 x (sA 8K + sB 8K)

    const int t    = threadIdx.x;
    const int lane = t & 63;
    const int wave = t >> 6;
    const int wr   = wave >> 1, wc = wave & 1;
    const int bm0  = blockIdx.x * 64;
    const int bn0  = blockIdx.y * 64;

    // staging coords: 512 x 16B chunks per 8KB tile -> 2 chunks/thread
    const int c0 = t, c1 = t + 256;
    const int r0 = c0 >> 3, cc0 = c0 & 7;
    const int r1 = c1 >> 3, cc1 = c1 & 7;
    const size_t aoff0 = (size_t)(bm0 + r0) * PRETRAIN + cc0 * 8;
    const size_t aoff1 = (size_t)(bm0 + r1) * PRETRAIN + cc1 * 8;
    const size_t boff0 = (size_t)(bn0 + r0) * PRETRAIN + cc0 * 8;
    const size_t boff1 = (size_t)(bn0 + r1) * PRETRAIN + cc1 * 8;
    const int wA0 = r0 * 128 + ((cc0 * 16) ^ ((r0 & 7) << 4));
    const int wA1 = r1 * 128 + ((cc1 * 16) ^ ((r1 & 7) << 4));

    f32x4 acc[2][2] = {};

    // prologue: tile 0 -> buf 0
    short8t va0 = *(const short8t*)(A + aoff0);
    short8t va1 = *(const short8t*)(A + aoff1);
    short8t vb0 = *(const short8t*)(WT + boff0);
    short8t vb1 = *(const short8t*)(WT + boff1);
    *(short8t*)(smem + wA0)        = va0;
    *(short8t*)(smem + wA1)        = va1;
    *(short8t*)(smem + 8192 + wA0) = vb0;
    *(short8t*)(smem + 8192 + wA1) = vb1;
    __syncthreads();

    for (int tt = 0; tt < 12; ++tt) {
        char* cbuf = smem + (tt & 1) * 16384;
        char* nbuf = smem + ((tt + 1) & 1) * 16384;
        if (tt < 11) {
            const int k0 = (tt + 1) * 64;   // issue next-tile loads (in flight over MFMA)
            va0 = *(const short8t*)(A + aoff0 + k0);
            va1 = *(const short8t*)(A + aoff1 + k0);
            vb0 = *(const short8t*)(WT + boff0 + k0);
            vb1 = *(const short8t*)(WT + boff1 + k0);
        }
#pragma unroll
        for (int ks = 0; ks < 2; ++ks) {
            const int kb = ks * 64 + (lane >> 4) * 16;
            short8t a[2], b[2];
#pragma unroll
            for (int mf = 0; mf < 2; ++mf) {
                int row = wr * 32 + mf * 16 + (lane & 15);
                a[mf] = *(const short8t*)(cbuf + row * 128 + (kb ^ ((row & 7) << 4)));
            }
#pragma unroll
            for (int nf = 0; nf < 2; ++nf) {
                int n = wc * 32 + nf * 16 + (lane & 15);
                b[nf] = *(const short8t*)(cbuf + 8192 + n * 128 + (kb ^ ((n & 7) << 4)));
            }
#pragma unroll
            for (int mf = 0; mf < 2; ++mf)
#pragma unroll
                for (int nf = 0; nf < 2; ++nf)
                    acc[mf][nf] = __builtin_amdgcn_mfma_f32_16x16x32_bf16(
                        a[mf], b[nf], acc[mf][nf], 0, 0, 0);
        }
        if (tt < 11) {                      // write next tile (other buffer; safe pre-barrier)
            *(short8t*)(nbuf + wA0)        = va0;
            *(short8t*)(nbuf + wA1)        = va1;
            *(short8t*)(nbuf + 8192 + wA0) = vb0;
            *(short8t*)(nbuf + 8192 + wA1) = vb1;
        }
        __syncthreads();
    }

    // epilogue: out += acc + proj_b  (C/D layout: col=lane&15, row=(lane>>4)*4+i)
#pragma unroll
    for (int mf = 0; mf < 2; ++mf)
#pragma unroll
        for (int nf = 0; nf < 2; ++nf)
#pragma unroll
            for (int i = 0; i < 4; ++i) {
                int mrow = bm0 + wr * 32 + mf * 16 + (lane >> 4) * 4 + i;
                int ncol = bn0 + wc * 32 + nf * 16 + (lane & 15);
                size_t o = (size_t)mrow * EMB + ncol;
                out[o] = out[o] + acc[mf][nf][i] + proj_b[ncol];
            }
}

extern "C" void kernel_launch(void* const* d_in, const int* in_sizes, int n_in,
                              void* d_out, int out_size, void* d_ws, size_t ws_size,
                              hipStream_t stream) {
    const int*   croutes = (const int*)d_in[0];
    // d_in[1] = tailcs (unused by reference)
    const float* cid_emb = (const float*)d_in[2];
    const float* weight  = (const float*)d_in[3];
    const float* content = (const float*)d_in[4];
    const float* proj_w  = (const float*)d_in[5];
    const float* proj_b  = (const float*)d_in[6];
    float*       out     = (float*)d_out;

    char* ws = (char*)d_ws;
    unsigned short* pooled = (unsigned short*)ws;                      // 12800*768*2 = 19,660,800 B
    unsigned short* WT     = (unsigned short*)(ws + 19660800);         // 256*768*2  =    393,216 B

    pool_kernel<<<BLK + 96, 256, 0, stream>>>(croutes, cid_emb, weight, content,
                                              proj_w, pooled, WT, out);
    gemm_kernel<<<dim3(200, 4), 256, 0, stream>>>(pooled, WT, proj_b, out);
}